// Round 7
// baseline (229.573 us; speedup 1.0000x reference)
//
#include <hip/hip_runtime.h>
#include <math.h>

// Problem constants
#define S_DIM 128
#define Q_DIM 64
#define P_DIM 64
#define D_DIM 256
#define NQ (S_DIM * Q_DIM)   // 8192 question rows
#define NS (S_DIM * P_DIM)   // 8192 sentence rows

typedef __attribute__((ext_vector_type(4))) float f32x4;
typedef __attribute__((ext_vector_type(8))) short bf16x8;
typedef __attribute__((ext_vector_type(8))) _Float16 f16x8;
typedef __attribute__((ext_vector_type(4))) _Float16 f16x4;

// ---------- helpers ----------
__device__ __forceinline__ unsigned short f2bf(float f) {
    unsigned int u = __float_as_uint(f);
    u = (u + 0x7fffu + ((u >> 16) & 1u)) >> 16;   // RNE (no NaN inputs here)
    return (unsigned short)u;
}
__device__ __forceinline__ float bf2f(unsigned short h) {
    return __uint_as_float(((unsigned int)h) << 16);
}
__device__ __forceinline__ void gload_lds16(const void* g, void* l) {
    __builtin_amdgcn_global_load_lds(
        (const __attribute__((address_space(1))) void*)g,
        (__attribute__((address_space(3))) void*)l, 16, 0, 0);
}

// ws layout:
//  floats [0, 8192)  total_exp (zeroed)
//  floats [8192,8320) den  [8320,8448) num  [8448,8450) loss_acc  [8452] ticket
//  halves from (ws+8704 floats):
//    qf [0,2097152)  sf [2097152,4194304)  stf [4194304,4227072)   (fp16, scaled)
//    q_hi @4718592  q_lo @6815744  s_hi @8912896  s_lo @11010048   (bf16, scaled)

// One wave per row: inv-norm; write fp16 scaled row (all tensors) and bf16
// hi/lo split (q,s only — consumed by the precision-sensitive qs2 pos path).
// exp(sim/TEMP) == exp2(dot of scaled rows) with per-row folded scale.
__global__ __launch_bounds__(256) void normsplit_kernel(
    const float* __restrict__ qm, const float* __restrict__ sm,
    const float* __restrict__ st, float* __restrict__ zero_region,
    _Float16* __restrict__ qf, _Float16* __restrict__ sf, _Float16* __restrict__ stf,
    unsigned short* __restrict__ q_hi, unsigned short* __restrict__ q_lo,
    unsigned short* __restrict__ s_hi, unsigned short* __restrict__ s_lo) {
    if (blockIdx.x < 34) {
        int i = blockIdx.x * 256 + threadIdx.x;
        if (i < 8456) zero_region[i] = 0.0f;
    }
    int row = blockIdx.x * 4 + (threadIdx.x >> 6);
    int lane = threadIdx.x & 63;
    const float* src;
    _Float16* fdst;
    unsigned short *hi = nullptr, *lo = nullptr;
    int r;
    if (row < NQ) {
        r = row; src = qm + (size_t)r * D_DIM; fdst = qf + (size_t)r * D_DIM;
        hi = q_hi + (size_t)r * D_DIM; lo = q_lo + (size_t)r * D_DIM;
    } else if (row < NQ + NS) {
        r = row - NQ; src = sm + (size_t)r * D_DIM; fdst = sf + (size_t)r * D_DIM;
        hi = s_hi + (size_t)r * D_DIM; lo = s_lo + (size_t)r * D_DIM;
    } else if (row < NQ + NS + S_DIM) {
        r = row - NQ - NS; src = st + (size_t)r * D_DIM; fdst = stf + (size_t)r * D_DIM;
    } else return;

    float4 v = reinterpret_cast<const float4*>(src)[lane];
    float ss = v.x * v.x + v.y * v.y + v.z * v.z + v.w * v.w;
    #pragma unroll
    for (int off = 32; off; off >>= 1) ss += __shfl_xor(ss, off);
    float inv = 1.0f / fmaxf(sqrtf(ss), 1e-12f);

    const float CF = sqrtf((1.0f / 0.07f) * 1.44269504088896f);
    float sc = inv * CF;
    float x[4] = {v.x * sc, v.y * sc, v.z * sc, v.w * sc};

    f16x4 fv;
    #pragma unroll
    for (int e = 0; e < 4; e++) fv[e] = (_Float16)x[e];
    reinterpret_cast<f16x4*>(fdst)[lane] = fv;

    if (hi) {
        ushort4 h, l;
        unsigned short* hp = &h.x; unsigned short* lp = &l.x;
        #pragma unroll
        for (int e = 0; e < 4; e++) {
            unsigned short hh = f2bf(x[e]);
            hp[e] = hh;
            lp[e] = f2bf(x[e] - bf2f(hh));
        }
        reinterpret_cast<ushort4*>(hi)[lane] = h;
        reinterpret_cast<ushort4*>(lo)[lane] = l;
    }
}

// Fused GEMM dispatch, 1088 blocks x 512 threads.
//  blocks [0,1024): A-pass — 256x256 tile, counted-vmcnt 4-buffer pipeline
//    (T3/T4/T5): stages issued 2 K-steps ahead, end-of-iter s_waitcnt vmcnt(4)
//    (never 0 mid-loop), raw s_barrier, setprio around MFMA clusters.
//  blocks [1024,1088): C-pass — 128x128 st x q tile, simple 2-phase dbuf.
// LDS per operand tile is k-group subtiled [kg][rows][16B]: conflict-free
// b128 frag reads (verified 0 conflicts in R6); global_load_lds writes linear
// dest, per-lane global SOURCE decodes the inverse mapping (rule #21).
__global__ __launch_bounds__(512, 2) void mfma_fused_kernel(
    const _Float16* __restrict__ qf, const _Float16* __restrict__ sf,
    const _Float16* __restrict__ stf,
    float* __restrict__ total_exp, float* __restrict__ den, float* __restrict__ num) {
    __shared__ __align__(16) char lds[4][2][16384];   // 128 KB
    const int tid = threadIdx.x;
    const int wid = tid >> 6, lane = tid & 63;
    const int lane15 = lane & 15;

    if (blockIdx.x >= 1024) {
        // ---------------- C-pass: den/num over 128 st-rows x 128 q-cols ----
        const int col0 = (int)(blockIdx.x - 1024) * 128;
        const int wrc = wid >> 2, wcc = wid & 3;   // 2x4 waves: 64-row x 32-col
        f32x4 acc[4][2];
        #pragma unroll
        for (int m = 0; m < 4; m++)
            #pragma unroll
            for (int n = 0; n < 2; n++) acc[m][n] = (f32x4){0.f, 0.f, 0.f, 0.f};

        auto CSTAGE = [&](int buf, int kc) {
            const int base = wid * 1024;           // wave-uniform dest byte
            const int o = base + lane * 16;
            const int kgs = o >> 11;
            const int r = (o >> 4) & 127;
            gload_lds16(stf + (((size_t)r) << 8) + kc + kgs * 8,
                        &lds[buf][0][0] + base);
            gload_lds16(qf + (((size_t)(col0 + r)) << 8) + kc + kgs * 8,
                        &lds[buf][1][0] + base);
        };
        CSTAGE(0, 0);
        __syncthreads();
        int cur = 0;
        for (int t = 0; t < 8; t++) {
            if (t < 7) CSTAGE(cur ^ 1, (t + 1) * 32);
            const char* Ab = &lds[cur][0][0];
            const char* Bb = &lds[cur][1][0];
            const int kplane = (lane >> 4) * 2048;
            f16x8 a[4], b[2];
            #pragma unroll
            for (int m = 0; m < 4; m++)
                a[m] = *reinterpret_cast<const f16x8*>(
                    Ab + kplane + (wrc * 64 + m * 16 + lane15) * 16);
            #pragma unroll
            for (int n = 0; n < 2; n++)
                b[n] = *reinterpret_cast<const f16x8*>(
                    Bb + kplane + (wcc * 32 + n * 16 + lane15) * 16);
            #pragma unroll
            for (int m = 0; m < 4; m++)
                #pragma unroll
                for (int n = 0; n < 2; n++)
                    acc[m][n] = __builtin_amdgcn_mfma_f32_16x16x32_f16(
                        a[m], b[n], acc[m][n], 0, 0, 0);
            __syncthreads();
            cur ^= 1;
        }
        #pragma unroll
        for (int m = 0; m < 4; m++) {
            #pragma unroll
            for (int j = 0; j < 4; j++) {
                const int grow = wrc * 64 + m * 16 + (lane >> 4) * 4 + j;
                float rs = 0.0f, nm = 0.0f;
                #pragma unroll
                for (int n = 0; n < 2; n++) {
                    float e = exp2f(acc[m][n][j]);
                    rs += e;
                    int col = col0 + wcc * 32 + n * 16 + lane15;
                    if ((col >> 6) == grow) nm += e;
                }
                #pragma unroll
                for (int off = 1; off < 16; off <<= 1) {
                    rs += __shfl_xor(rs, off);
                    nm += __shfl_xor(nm, off);
                }
                if (lane15 == 0) {
                    atomicAdd(&den[grow], rs);
                    atomicAdd(&num[grow], nm);
                }
            }
        }
        return;
    }

    // ---------------- A-pass: total_exp over 256 q-rows x 256 s-cols ----
    const int bid = blockIdx.x;
    const int swz = (bid & 7) * 128 + (bid >> 3);   // bijective (1024 % 8 == 0)
    const int row0 = (swz >> 5) * 256;
    const int col0 = (swz & 31) * 256;
    const int wr = wid >> 2, wc = wid & 3;          // 2x4 waves: 128-row x 64-col

    f32x4 acc[8][4];
    #pragma unroll
    for (int m = 0; m < 8; m++)
        #pragma unroll
        for (int n = 0; n < 4; n++) acc[m][n] = (f32x4){0.f, 0.f, 0.f, 0.f};

    const int kplane = (lane >> 4) * 4096;
    const int aoff = kplane + (wr * 128 + lane15) * 16;   // + m*256
    const int boff = kplane + (wc * 64 + lane15) * 16;    // + n*256

    // Stage one operand (op 0=A rows, 1=B cols) of K-step kt into lds[buf][op].
    // Linear dest (2x 1KB chunks per wave); source decodes the subtile mapping.
    auto STAGE = [&](int buf, int kt, int op) {
        const int kc = kt * 32;
        #pragma unroll
        for (int i = 0; i < 2; i++) {
            const int base = (i * 8 + wid) * 1024;   // wave-uniform dest byte
            const int o = base + lane * 16;
            const int kgs = o >> 12;                  // 0..3 k-group plane
            const int r = (o >> 4) & 255;             // tile row
            const _Float16* src = op ? sf : qf;
            const int rb = op ? col0 : row0;
            gload_lds16(src + (((size_t)(rb + r)) << 8) + kc + kgs * 8,
                        &lds[buf][op][0] + base);
        }
    };

    // Prologue: stage K0 (buf0) and K1 (buf1); wait for K0 only (4 newest fly).
    STAGE(0, 0, 0); STAGE(0, 0, 1);
    STAGE(1, 1, 0); STAGE(1, 1, 1);
    asm volatile("s_waitcnt vmcnt(4)" ::: "memory");
    __builtin_amdgcn_s_barrier();

    #pragma unroll
    for (int kt = 0; kt < 8; kt++) {
        const int cur = kt & 3;
        const char* Ab = &lds[cur][0][0];
        const char* Bb = &lds[cur][1][0];
        f16x8 a[4], b[4];
        // ---- phase 0: frags m0-3 + b0-3; stage A of kt+2 ----
        #pragma unroll
        for (int m = 0; m < 4; m++)
            a[m] = *reinterpret_cast<const f16x8*>(Ab + aoff + m * 256);
        #pragma unroll
        for (int n = 0; n < 4; n++)
            b[n] = *reinterpret_cast<const f16x8*>(Bb + boff + n * 256);
        if (kt < 6) STAGE((kt + 2) & 3, kt + 2, 0);
        __builtin_amdgcn_s_barrier();
        __builtin_amdgcn_s_setprio(1);
        #pragma unroll
        for (int m = 0; m < 4; m++)
            #pragma unroll
            for (int n = 0; n < 4; n++)
                acc[m][n] = __builtin_amdgcn_mfma_f32_16x16x32_f16(
                    a[m], b[n], acc[m][n], 0, 0, 0);
        __builtin_amdgcn_s_setprio(0);
        __builtin_amdgcn_s_barrier();
        // ---- phase 1: frags m4-7 (b reused); stage B of kt+2 ----
        #pragma unroll
        for (int m = 0; m < 4; m++)
            a[m] = *reinterpret_cast<const f16x8*>(Ab + aoff + (m + 4) * 256);
        if (kt < 6) STAGE((kt + 2) & 3, kt + 2, 1);
        __builtin_amdgcn_s_barrier();
        __builtin_amdgcn_s_setprio(1);
        #pragma unroll
        for (int m = 0; m < 4; m++)
            #pragma unroll
            for (int n = 0; n < 4; n++)
                acc[m + 4][n] = __builtin_amdgcn_mfma_f32_16x16x32_f16(
                    a[m], b[n], acc[m + 4][n], 0, 0, 0);
        __builtin_amdgcn_s_setprio(0);
        // End-of-iter: make buf[(kt+1)&3] ready. FIFO: wait this wave's 4
        // oldest (= prev iter's stages); this iter's 4 stay in flight.
        if (kt < 6) {
            asm volatile("s_waitcnt vmcnt(4)" ::: "memory");
        } else if (kt == 6) {
            asm volatile("s_waitcnt vmcnt(0)" ::: "memory");   // tail drain
        }
        if (kt < 7) __builtin_amdgcn_s_barrier();
    }

    // Epilogue: exp2 + row-sum over this block's 256 cols; one atomic per
    // row per wave. C/D layout (16x16): col = lane&15, row = (lane>>4)*4+reg.
    #pragma unroll
    for (int m = 0; m < 8; m++) {
        #pragma unroll
        for (int j = 0; j < 4; j++) {
            const int grow = row0 + wr * 128 + m * 16 + (lane >> 4) * 4 + j;
            float rs = 0.0f;
            #pragma unroll
            for (int n = 0; n < 4; n++) rs += exp2f(acc[m][n][j]);
            #pragma unroll
            for (int off = 1; off < 16; off <<= 1) rs += __shfl_xor(rs, off);
            if (lane15 == 0) atomicAdd(&total_exp[grow], rs);
        }
    }
}

// qs_loss + finalize. 256 blocks x 128 threads; block = half a section.
// pos/own_exp recomputed in bf16x3 (precision-sensitive path), straight from
// L2; all 16 A-frags preloaded for ILP. Last block (ticket) finalizes.
__global__ __launch_bounds__(128) void qs2_kernel(
    const unsigned short* __restrict__ q_hi, const unsigned short* __restrict__ q_lo,
    const unsigned short* __restrict__ s_hi, const unsigned short* __restrict__ s_lo,
    const float* __restrict__ total_exp, const float* __restrict__ den,
    const float* __restrict__ num, double* __restrict__ loss_acc,
    unsigned int* __restrict__ ticket, float* __restrict__ out) {
    const int s = blockIdx.x >> 1;
    const int tid = threadIdx.x;
    const int wid2 = ((blockIdx.x & 1) << 1) + (tid >> 6);   // 0..3 within section
    const int lane = tid & 63;
    __shared__ double wsum[2];
    __shared__ float w2[2];
    __shared__ unsigned int winner_s;

    const int arow = s * 64 + wid2 * 16 + (lane & 15);
    const int koff = (lane >> 4) * 8;

    bf16x8 ah[8], al[8];
    #pragma unroll
    for (int k8 = 0; k8 < 8; k8++) {
        ah[k8] = *reinterpret_cast<const bf16x8*>(&q_hi[(size_t)arow * D_DIM + k8 * 32 + koff]);
        al[k8] = *reinterpret_cast<const bf16x8*>(&q_lo[(size_t)arow * D_DIM + k8 * 32 + koff]);
    }

    f32x4 acc[4];
    #pragma unroll
    for (int n = 0; n < 4; n++) acc[n] = (f32x4){0.f, 0.f, 0.f, 0.f};
    #pragma unroll
    for (int n = 0; n < 4; n++) {
        const int brow = s * 64 + n * 16 + (lane & 15);
        #pragma unroll
        for (int k8 = 0; k8 < 8; k8++) {
            bf16x8 bh = *reinterpret_cast<const bf16x8*>(&s_hi[(size_t)brow * D_DIM + k8 * 32 + koff]);
            bf16x8 bl = *reinterpret_cast<const bf16x8*>(&s_lo[(size_t)brow * D_DIM + k8 * 32 + koff]);
            acc[n] = __builtin_amdgcn_mfma_f32_16x16x32_bf16(ah[k8], bh, acc[n], 0, 0, 0);
            acc[n] = __builtin_amdgcn_mfma_f32_16x16x32_bf16(ah[k8], bl, acc[n], 0, 0, 0);
            acc[n] = __builtin_amdgcn_mfma_f32_16x16x32_bf16(al[k8], bh, acc[n], 0, 0, 0);
        }
    }

    const float term2 = expf(-1.0f / 0.07f) * (float)(NS - 1);
    double lacc = 0.0;
    #pragma unroll
    for (int j = 0; j < 4; j++) {
        float e[4];
        float part = 0.0f;
        #pragma unroll
        for (int n = 0; n < 4; n++) { e[n] = exp2f(acc[n][j]); part += e[n]; }
        #pragma unroll
        for (int off = 1; off < 16; off <<= 1) part += __shfl_xor(part, off);
        const int trow = s * 64 + wid2 * 16 + (lane >> 4) * 4 + j;
        const float neg = total_exp[trow] - part;
        #pragma unroll
        for (int n = 0; n < 4; n++) {
            float posv = e[n];
            float t1 = fmaf(-0.1f, posv, neg / 0.9f);
            float Ng = fmaxf(fmaxf(t1, term2), 1e-8f);
            lacc += (double)(-logf(posv / (posv + Ng)));
        }
    }
    #pragma unroll
    for (int off = 1; off < 64; off <<= 1) lacc += __shfl_xor(lacc, off);
    if (lane == 0) wsum[tid >> 6] = lacc;
    __syncthreads();
    if (tid == 0) {
        atomicAdd(loss_acc, wsum[0] + wsum[1]);
        __threadfence();
        winner_s = atomicAdd(ticket, 1u);
    }
    __syncthreads();
    if (winner_s == 255) {
        __threadfence();   // acquire: all other blocks' loss atomics visible
        float l = -logf(num[tid] / den[tid]);   // tid = 0..127 = section
        #pragma unroll
        for (int off = 1; off < 64; off <<= 1) l += __shfl_xor(l, off);
        if ((tid & 63) == 0) w2[tid >> 6] = l;
        __syncthreads();
        if (tid == 0) out[0] = (float)(loss_acc[0] + (double)(w2[0] + w2[1]));
        // at_loss = -log(x/x) = 0 exactly; omitted.
    }
}

extern "C" void kernel_launch(void* const* d_in, const int* in_sizes, int n_in,
                              void* d_out, int out_size, void* d_ws, size_t ws_size,
                              hipStream_t stream) {
    const float* st = (const float*)d_in[1];   // [128,256]
    const float* qm = (const float*)d_in[2];   // [128,64,256]
    const float* sm = (const float*)d_in[3];   // [128,64,256]

    float* ws        = (float*)d_ws;
    float* total_exp = ws;
    float* den       = ws + 8192;
    float* num       = ws + 8320;
    double* loss_acc = (double*)(ws + 8448);
    unsigned int* ticket = (unsigned int*)(ws + 8452);
    _Float16* fbase = (_Float16*)(ws + 8704);
    _Float16* qf  = fbase;
    _Float16* sf  = fbase + 2097152;
    _Float16* stf = fbase + 4194304;
    unsigned short* b16 = (unsigned short*)fbase;
    unsigned short* q_hi = b16 + 4718592;
    unsigned short* q_lo = b16 + 6815744;
    unsigned short* s_hi = b16 + 8912896;
    unsigned short* s_lo = b16 + 11010048;
    float* out = (float*)d_out;

    // 1: zero accumulators + norm + fp16/bf16-split writes
    hipLaunchKernelGGL(normsplit_kernel, dim3(4128), dim3(256), 0, stream,
                       qm, sm, st, ws, qf, sf, stf, q_hi, q_lo, s_hi, s_lo);
    // 2: fused A-pass (counted-vmcnt 256² pipeline) + C-pass (64 tail blocks)
    hipLaunchKernelGGL(mfma_fused_kernel, dim3(1088), dim3(512), 0, stream,
                       qf, sf, stf, total_exp, den, num);
    // 3: qs_loss (bf16x3 pos path) + finalize (ticketed last block)
    hipLaunchKernelGGL(qs2_kernel, dim3(256), dim3(128), 0, stream,
                       q_hi, q_lo, s_hi, s_lo, total_exp, den, num,
                       loss_acc, ticket, out);
}

// Round 8
// 158.039 us; speedup vs baseline: 1.4526x; 1.4526x over previous
//
#include <hip/hip_runtime.h>
#include <math.h>

// Problem constants
#define S_DIM 128
#define Q_DIM 64
#define P_DIM 64
#define D_DIM 256
#define NQ (S_DIM * Q_DIM)   // 8192 question rows
#define NS (S_DIM * P_DIM)   // 8192 sentence rows

typedef __attribute__((ext_vector_type(4))) float f32x4;
typedef __attribute__((ext_vector_type(8))) short bf16x8;
typedef __attribute__((ext_vector_type(8))) _Float16 f16x8;
typedef __attribute__((ext_vector_type(4))) _Float16 f16x4;

// ---------- helpers ----------
__device__ __forceinline__ unsigned short f2bf(float f) {
    unsigned int u = __float_as_uint(f);
    u = (u + 0x7fffu + ((u >> 16) & 1u)) >> 16;   // RNE (no NaN inputs here)
    return (unsigned short)u;
}
__device__ __forceinline__ float bf2f(unsigned short h) {
    return __uint_as_float(((unsigned int)h) << 16);
}
__device__ __forceinline__ void gload_lds16(const void* g, void* l) {
    __builtin_amdgcn_global_load_lds(
        (const __attribute__((address_space(1))) void*)g,
        (__attribute__((address_space(3))) void*)l, 16, 0, 0);
}

// ws layout:
//  floats [0, 8192)  total_exp (zeroed)
//  floats [8192,8320) den  [8320,8448) num  [8448,8450) loss_acc  [8452] ticket
//  halves from (ws+8704 floats):
//    qf [0,2097152)  sf [2097152,4194304)  stf [4194304,4227072)   (fp16, scaled)
//    q_hi @4718592  q_lo @6815744  s_hi @8912896  s_lo @11010048   (bf16, scaled)

// One wave per row: inv-norm; write fp16 scaled row (all tensors) and bf16
// hi/lo split (q,s only — consumed by the precision-sensitive qs2 pos path).
// exp(sim/TEMP) == exp2(dot of scaled rows) with per-row folded scale.
__global__ __launch_bounds__(256) void normsplit_kernel(
    const float* __restrict__ qm, const float* __restrict__ sm,
    const float* __restrict__ st, float* __restrict__ zero_region,
    _Float16* __restrict__ qf, _Float16* __restrict__ sf, _Float16* __restrict__ stf,
    unsigned short* __restrict__ q_hi, unsigned short* __restrict__ q_lo,
    unsigned short* __restrict__ s_hi, unsigned short* __restrict__ s_lo) {
    if (blockIdx.x < 34) {
        int i = blockIdx.x * 256 + threadIdx.x;
        if (i < 8456) zero_region[i] = 0.0f;
    }
    int row = blockIdx.x * 4 + (threadIdx.x >> 6);
    int lane = threadIdx.x & 63;
    const float* src;
    _Float16* fdst;
    unsigned short *hi = nullptr, *lo = nullptr;
    int r;
    if (row < NQ) {
        r = row; src = qm + (size_t)r * D_DIM; fdst = qf + (size_t)r * D_DIM;
        hi = q_hi + (size_t)r * D_DIM; lo = q_lo + (size_t)r * D_DIM;
    } else if (row < NQ + NS) {
        r = row - NQ; src = sm + (size_t)r * D_DIM; fdst = sf + (size_t)r * D_DIM;
        hi = s_hi + (size_t)r * D_DIM; lo = s_lo + (size_t)r * D_DIM;
    } else if (row < NQ + NS + S_DIM) {
        r = row - NQ - NS; src = st + (size_t)r * D_DIM; fdst = stf + (size_t)r * D_DIM;
    } else return;

    float4 v = reinterpret_cast<const float4*>(src)[lane];
    float ss = v.x * v.x + v.y * v.y + v.z * v.z + v.w * v.w;
    #pragma unroll
    for (int off = 32; off; off >>= 1) ss += __shfl_xor(ss, off);
    float inv = 1.0f / fmaxf(sqrtf(ss), 1e-12f);

    const float CF = sqrtf((1.0f / 0.07f) * 1.44269504088896f);
    float sc = inv * CF;
    float x[4] = {v.x * sc, v.y * sc, v.z * sc, v.w * sc};

    f16x4 fv;
    #pragma unroll
    for (int e = 0; e < 4; e++) fv[e] = (_Float16)x[e];
    reinterpret_cast<f16x4*>(fdst)[lane] = fv;

    if (hi) {
        ushort4 h, l;
        unsigned short* hp = &h.x; unsigned short* lp = &l.x;
        #pragma unroll
        for (int e = 0; e < 4; e++) {
            unsigned short hh = f2bf(x[e]);
            hp[e] = hh;
            lp[e] = f2bf(x[e] - bf2f(hh));
        }
        reinterpret_cast<ushort4*>(hi)[lane] = h;
        reinterpret_cast<ushort4*>(lo)[lane] = l;
    }
}

// Streaming fp16 MFMA GEMM + fused exp2/rowsum. 576 blocks x 512 threads.
//  blocks [64,576): A-pass. Block owns 128 q-rows (A-frags for FULL K=256 in
//    VGPRs — no LDS for A), streams 16 B-tiles (64 s-cols x K, 32 KB) from its
//    XCD-local column panel (colgroup = bid&7 -> L2-resident, 64 blocks share).
//  blocks [0,64): C-pass. Same loop, A=stf (128 st-rows), 2 q-col tiles each;
//    short blocks dispatched first so they backfill the schedule.
// Per tile-iter: stage next tile (4 gload_lds/wave) -> 8 k-chunks x {2
// ds_read_b128 + 4 MFMA} (~600cy, covers the load latency) -> __syncthreads
// (its vmcnt(0) drain is then ~free). 2-buffer ledger: buf[(t+1)&1] staged at
// iter t was last read at iter t-1 (reads retire before that barrier); buf[t&1]
// staged at t-1 is drained by t-1's barrier vmcnt(0).
// LDS B layout [chunk 8][kg 4][col 64][16B]: linear gload_lds dest decodes to
// per-lane source (rule #21); quarter-wave b128 reads are 256B-contiguous ->
// conflict-free (0 conflicts measured on this family in R6).
// Epilogue per tile in registers; atomics once per block.
__global__ __launch_bounds__(512, 4) void mfma_stream_kernel(
    const _Float16* __restrict__ qf, const _Float16* __restrict__ sf,
    const _Float16* __restrict__ stf,
    float* __restrict__ total_exp, float* __restrict__ den, float* __restrict__ num) {
    __shared__ __align__(16) char lds[2][32768];   // 64 KB -> 2 blocks/CU
    const int tid = threadIdx.x;
    const int wid = tid >> 6, lane = tid & 63;
    const int lane15 = lane & 15, kg = lane >> 4;
    const int wr = wid >> 1, wc = wid & 1;   // 4 row-waves x 2 col-waves

    const bool cpass = (blockIdx.x < 64);
    const _Float16* A;
    const _Float16* B;
    int row0, colbase, ntiles;
    if (cpass) {
        A = stf; B = qf; row0 = 0;
        colbase = (int)blockIdx.x * 128; ntiles = 2;
    } else {
        const int b = (int)blockIdx.x - 64;
        A = qf; B = sf;
        row0 = (b >> 3) * 128;            // 64 row-blocks
        colbase = (b & 7) * 1024;         // col-group == XCD (bid%8)
        ntiles = 16;
    }

    // A-fragments for this wave's 32 rows, full K, in registers (64 VGPR).
    f16x8 af[2][8];
    {
        const _Float16* ap = A + (((size_t)(row0 + wr * 32 + lane15)) << 8) + kg * 8;
        #pragma unroll
        for (int mb = 0; mb < 2; mb++)
            #pragma unroll
            for (int c = 0; c < 8; c++)
                af[mb][c] = *reinterpret_cast<const f16x8*>(ap + mb * 16 * 256 + c * 32);
    }

    // Stage B-tile `t` into lds[buf]: per wave 4 x 1KB chunks. Linear dest byte
    // o = wid*4096 + i*1024 + lane*16 decodes to (chunk=wid, kg=i, col=lane).
    auto STAGE = [&](int buf, int t) {
        const _Float16* src = B + (((size_t)(colbase + t * 64 + lane)) << 8) + wid * 32;
        #pragma unroll
        for (int i = 0; i < 4; i++)
            gload_lds16(src + i * 8, &lds[buf][0] + wid * 4096 + i * 1024);
    };

    float rs[2][4] = {{0.f, 0.f, 0.f, 0.f}, {0.f, 0.f, 0.f, 0.f}};
    float nm[2][4] = {{0.f, 0.f, 0.f, 0.f}, {0.f, 0.f, 0.f, 0.f}};

    STAGE(0, 0);
    __syncthreads();   // drains A-loads + tile0 stage together (one latency)

    for (int t = 0; t < ntiles; t++) {
        if (t + 1 < ntiles) STAGE((t + 1) & 1, t + 1);
        const char* Bb = &lds[t & 1][0];

        f32x4 acc[2][2];
        #pragma unroll
        for (int mb = 0; mb < 2; mb++)
            #pragma unroll
            for (int n = 0; n < 2; n++) acc[mb][n] = (f32x4){0.f, 0.f, 0.f, 0.f};

        #pragma unroll
        for (int c = 0; c < 8; c++) {
            f16x8 bf[2];
            #pragma unroll
            for (int n = 0; n < 2; n++)
                bf[n] = *reinterpret_cast<const f16x8*>(
                    Bb + c * 4096 + kg * 1024 + (wc * 32 + n * 16 + lane15) * 16);
            #pragma unroll
            for (int mb = 0; mb < 2; mb++)
                #pragma unroll
                for (int n = 0; n < 2; n++)
                    acc[mb][n] = __builtin_amdgcn_mfma_f32_16x16x32_f16(
                        af[mb][c], bf[n], acc[mb][n], 0, 0, 0);
        }

        // Per-tile epilogue in registers (C/D: col=lane15, row=(lane>>4)*4+j).
        #pragma unroll
        for (int mb = 0; mb < 2; mb++)
            #pragma unroll
            for (int j = 0; j < 4; j++) {
                const int grow = row0 + wr * 32 + mb * 16 + kg * 4 + j;
                #pragma unroll
                for (int n = 0; n < 2; n++) {
                    float e = exp2f(acc[mb][n][j]);
                    rs[mb][j] += e;
                    if (cpass) {
                        int col = colbase + t * 64 + wc * 32 + n * 16 + lane15;
                        if ((col >> 6) == grow) nm[mb][j] += e;
                    }
                }
            }
        __syncthreads();   // vmcnt(0): next-tile loads issued ~600cy ago; free
    }

    // Final: reduce over the 16-lane col group, one atomic per row.
    #pragma unroll
    for (int mb = 0; mb < 2; mb++)
        #pragma unroll
        for (int j = 0; j < 4; j++) {
            float v = rs[mb][j], w = nm[mb][j];
            #pragma unroll
            for (int off = 1; off < 16; off <<= 1) {
                v += __shfl_xor(v, off);
                if (cpass) w += __shfl_xor(w, off);
            }
            if (lane15 == 0) {
                const int grow = row0 + wr * 32 + mb * 16 + kg * 4 + j;
                if (cpass) {
                    atomicAdd(&den[grow], v);
                    atomicAdd(&num[grow], w);
                } else {
                    atomicAdd(&total_exp[grow], v);
                }
            }
        }
}

// qs_loss + finalize. 256 blocks x 128 threads; block = half a section.
// pos/own_exp recomputed in bf16x3 (precision-sensitive path), straight from
// L2; all 16 A-frags preloaded for ILP. Last block (ticket) finalizes.
__global__ __launch_bounds__(128) void qs2_kernel(
    const unsigned short* __restrict__ q_hi, const unsigned short* __restrict__ q_lo,
    const unsigned short* __restrict__ s_hi, const unsigned short* __restrict__ s_lo,
    const float* __restrict__ total_exp, const float* __restrict__ den,
    const float* __restrict__ num, double* __restrict__ loss_acc,
    unsigned int* __restrict__ ticket, float* __restrict__ out) {
    const int s = blockIdx.x >> 1;
    const int tid = threadIdx.x;
    const int wid2 = ((blockIdx.x & 1) << 1) + (tid >> 6);   // 0..3 within section
    const int lane = tid & 63;
    __shared__ double wsum[2];
    __shared__ float w2[2];
    __shared__ unsigned int winner_s;

    const int arow = s * 64 + wid2 * 16 + (lane & 15);
    const int koff = (lane >> 4) * 8;

    bf16x8 ah[8], al[8];
    #pragma unroll
    for (int k8 = 0; k8 < 8; k8++) {
        ah[k8] = *reinterpret_cast<const bf16x8*>(&q_hi[(size_t)arow * D_DIM + k8 * 32 + koff]);
        al[k8] = *reinterpret_cast<const bf16x8*>(&q_lo[(size_t)arow * D_DIM + k8 * 32 + koff]);
    }

    f32x4 acc[4];
    #pragma unroll
    for (int n = 0; n < 4; n++) acc[n] = (f32x4){0.f, 0.f, 0.f, 0.f};
    #pragma unroll
    for (int n = 0; n < 4; n++) {
        const int brow = s * 64 + n * 16 + (lane & 15);
        #pragma unroll
        for (int k8 = 0; k8 < 8; k8++) {
            bf16x8 bh = *reinterpret_cast<const bf16x8*>(&s_hi[(size_t)brow * D_DIM + k8 * 32 + koff]);
            bf16x8 bl = *reinterpret_cast<const bf16x8*>(&s_lo[(size_t)brow * D_DIM + k8 * 32 + koff]);
            acc[n] = __builtin_amdgcn_mfma_f32_16x16x32_bf16(ah[k8], bh, acc[n], 0, 0, 0);
            acc[n] = __builtin_amdgcn_mfma_f32_16x16x32_bf16(ah[k8], bl, acc[n], 0, 0, 0);
            acc[n] = __builtin_amdgcn_mfma_f32_16x16x32_bf16(al[k8], bh, acc[n], 0, 0, 0);
        }
    }

    const float term2 = expf(-1.0f / 0.07f) * (float)(NS - 1);
    double lacc = 0.0;
    #pragma unroll
    for (int j = 0; j < 4; j++) {
        float e[4];
        float part = 0.0f;
        #pragma unroll
        for (int n = 0; n < 4; n++) { e[n] = exp2f(acc[n][j]); part += e[n]; }
        #pragma unroll
        for (int off = 1; off < 16; off <<= 1) part += __shfl_xor(part, off);
        const int trow = s * 64 + wid2 * 16 + (lane >> 4) * 4 + j;
        const float neg = total_exp[trow] - part;
        #pragma unroll
        for (int n = 0; n < 4; n++) {
            float posv = e[n];
            float t1 = fmaf(-0.1f, posv, neg / 0.9f);
            float Ng = fmaxf(fmaxf(t1, term2), 1e-8f);
            lacc += (double)(-logf(posv / (posv + Ng)));
        }
    }
    #pragma unroll
    for (int off = 1; off < 64; off <<= 1) lacc += __shfl_xor(lacc, off);
    if (lane == 0) wsum[tid >> 6] = lacc;
    __syncthreads();
    if (tid == 0) {
        atomicAdd(loss_acc, wsum[0] + wsum[1]);
        __threadfence();
        winner_s = atomicAdd(ticket, 1u);
    }
    __syncthreads();
    if (winner_s == 255) {
        __threadfence();   // acquire: all other blocks' loss atomics visible
        float l = -logf(num[tid] / den[tid]);   // tid = 0..127 = section
        #pragma unroll
        for (int off = 1; off < 64; off <<= 1) l += __shfl_xor(l, off);
        if ((tid & 63) == 0) w2[tid >> 6] = l;
        __syncthreads();
        if (tid == 0) out[0] = (float)(loss_acc[0] + (double)(w2[0] + w2[1]));
        // at_loss = -log(x/x) = 0 exactly; omitted.
    }
}

extern "C" void kernel_launch(void* const* d_in, const int* in_sizes, int n_in,
                              void* d_out, int out_size, void* d_ws, size_t ws_size,
                              hipStream_t stream) {
    const float* st = (const float*)d_in[1];   // [128,256]
    const float* qm = (const float*)d_in[2];   // [128,64,256]
    const float* sm = (const float*)d_in[3];   // [128,64,256]

    float* ws        = (float*)d_ws;
    float* total_exp = ws;
    float* den       = ws + 8192;
    float* num       = ws + 8320;
    double* loss_acc = (double*)(ws + 8448);
    unsigned int* ticket = (unsigned int*)(ws + 8452);
    _Float16* fbase = (_Float16*)(ws + 8704);
    _Float16* qf  = fbase;
    _Float16* sf  = fbase + 2097152;
    _Float16* stf = fbase + 4194304;
    unsigned short* b16 = (unsigned short*)fbase;
    unsigned short* q_hi = b16 + 4718592;
    unsigned short* q_lo = b16 + 6815744;
    unsigned short* s_hi = b16 + 8912896;
    unsigned short* s_lo = b16 + 11010048;
    float* out = (float*)d_out;

    // 1: zero accumulators + norm + fp16/bf16-split writes
    hipLaunchKernelGGL(normsplit_kernel, dim3(4128), dim3(256), 0, stream,
                       qm, sm, st, ws, qf, sf, stf, q_hi, q_lo, s_hi, s_lo);
    // 2: streaming GEMM: A-pass (total_exp) + C-pass (den/num)
    hipLaunchKernelGGL(mfma_stream_kernel, dim3(576), dim3(512), 0, stream,
                       qf, sf, stf, total_exp, den, num);
    // 3: qs_loss (bf16x3 pos path) + finalize (ticketed last block)
    hipLaunchKernelGGL(qs2_kernel, dim3(256), dim3(128), 0, stream,
                       q_hi, q_lo, s_hi, s_lo, total_exp, den, num,
                       loss_acc, ticket, out);
}